// Round 10
// baseline (357.795 us; speedup 1.0000x reference)
//
#include <hip/hip_runtime.h>

// ---- problem constants ----
#define B_    2
#define N_    2049
#define NPAD  2112          // keys padded to multiple of 64
#define D_    1024
#define H_    16
#define DH    64
#define MROWS (B_ * N_)     // 4098
#define MPAD  4224          // MROWS padded to multiple of 128 (GEMM block tile)
#define QSCALE 0.18033688011117674f   // 0.125 * log2(e): softmax in exp2 domain

using bf16x8 = __attribute__((ext_vector_type(8))) short;
using f32x4  = __attribute__((ext_vector_type(4))) float;

#define AS1 __attribute__((address_space(1)))
#define AS3 __attribute__((address_space(3)))

__device__ __forceinline__ float bf2f(short s) {
  union { unsigned u; float f; } a; a.u = ((unsigned)(unsigned short)s) << 16; return a.f;
}
__device__ __forceinline__ short f2bf(float f) {
  union { float f; unsigned u; } a; a.f = f;
  unsigned r = a.u + 0x7fffu + ((a.u >> 16) & 1u);   // round-to-nearest-even
  return (short)(r >> 16);
}
// truncation pack of two fp32 -> bf16x2
__device__ __forceinline__ unsigned pack_trunc(float lo, float hi) {
  union { float f; unsigned u; } a, b; a.f = lo; b.f = hi;
  return (b.u & 0xffff0000u) | (a.u >> 16);
}
// hardware 2^x (v_exp_f32)
__device__ __forceinline__ float hexp2(float x) { return __builtin_amdgcn_exp2f(x); }
// async global->LDS DMA, 16 B/lane (GEMM staging)
__device__ __forceinline__ void dma16(const short* g, AS3 short* l) {
  __builtin_amdgcn_global_load_lds((const AS1 unsigned*)g, (AS3 unsigned*)l, 16, 0, 0);
}

// ---------------- LayerNorm: fp32 in -> bf16 out ----------------
__global__ __launch_bounds__(256) void ln_kernel(const float* __restrict__ x,
                                                 const float* __restrict__ gamma,
                                                 const float* __restrict__ beta,
                                                 short* __restrict__ xn) {
  int row = blockIdx.x;
  int tid = threadIdx.x;
  const float4 v = ((const float4*)(x + (size_t)row * D_))[tid];
  float s  = v.x + v.y + v.z + v.w;
  float ss = v.x * v.x + v.y * v.y + v.z * v.z + v.w * v.w;
  for (int o = 1; o < 64; o <<= 1) { s += __shfl_xor(s, o, 64); ss += __shfl_xor(ss, o, 64); }
  __shared__ float sb[4], s2b[4];
  int wid = tid >> 6;
  if ((tid & 63) == 0) { sb[wid] = s; s2b[wid] = ss; }
  __syncthreads();
  float st  = sb[0] + sb[1] + sb[2] + sb[3];
  float sst = s2b[0] + s2b[1] + s2b[2] + s2b[3];
  float mu  = st * (1.0f / D_);
  float var = sst * (1.0f / D_) - mu * mu;
  float rs  = rsqrtf(var + 1e-5f);
  const float4 g  = ((const float4*)gamma)[tid];
  const float4 be = ((const float4*)beta)[tid];
  short4 o4;
  o4.x = f2bf((v.x - mu) * rs * g.x + be.x);
  o4.y = f2bf((v.y - mu) * rs * g.y + be.y);
  o4.z = f2bf((v.z - mu) * rs * g.z + be.z);
  o4.w = f2bf((v.w - mu) * rs * g.w + be.w);
  ((short4*)(xn + (size_t)row * D_))[tid] = o4;
}

// ------------- transpose+cast: fp32 [K][Nn] -> bf16 [Nn][K] -------------
__global__ __launch_bounds__(256) void transpose_cast(const float* __restrict__ in,
                                                      short* __restrict__ out,
                                                      int K, int Nn) {
  int idx = blockIdx.x * 256 + threadIdx.x;
  if (idx >= K * Nn) return;
  int kk = idx / Nn, nn = idx - kk * Nn;
  out[(size_t)nn * K + kk] = f2bf(in[idx]);
}

// ------------- m97-style 128x128 GEMM: C[M][Ncols] = A[M][K] * BT[Ncols][K]^T -------------
#define BM 128
#define BK 32
template <typename OutT>
__global__ __launch_bounds__(256) void gemm128(const short* __restrict__ A,
                                               const short* __restrict__ BT,
                                               OutT* __restrict__ C,
                                               int Mstore, int Ncols, int K) {
  int lane = threadIdx.x & 63, wid = threadIdx.x >> 6;
  int quad = lane >> 4, l16 = lane & 15;
  int wr = wid >> 1, wc = wid & 1;
  int m0 = blockIdx.x * BM;
  int n0 = blockIdx.y * BM;

  __shared__ __align__(16) short Abuf[2][BM * BK];   // [row][k] row-major, 8 KB each
  __shared__ __align__(16) short Bbuf[2][BM * BK];
  AS3 short* AbufL = (AS3 short*)&Abuf[0][0];
  AS3 short* BbufL = (AS3 short*)&Bbuf[0][0];

  f32x4 acc[4][4] = {};

  int lrow = lane >> 2, lcol8 = (lane & 3) * 8;
  const short* Ag = A  + (size_t)(m0 + lrow) * K + lcol8;
  const short* Bg = BT + (size_t)(n0 + lrow) * K + lcol8;

  auto stage = [&](int kt, int bb) {
    int k0 = kt * BK;
    #pragma unroll
    for (int i = 0; i < 2; ++i) {
      int j = wid * 2 + i;                  // slab 0..7 (16 rows each)
      dma16(Ag + (size_t)j * 16 * K + k0, AbufL + bb * (BM * BK) + j * 512);
      dma16(Bg + (size_t)j * 16 * K + k0, BbufL + bb * (BM * BK) + j * 512);
    }
  };

  stage(0, 0);
  __syncthreads();

  int KT = K / BK;
  for (int kt = 0; kt < KT; ++kt) {
    int cur = kt & 1;
    if (kt + 1 < KT) stage(kt + 1, cur ^ 1);
    const short* Ab = &Abuf[cur][0];
    const short* Bb = &Bbuf[cur][0];
    bf16x8 af[4], bfr[4];
    #pragma unroll
    for (int s = 0; s < 4; ++s)
      af[s] = *(const bf16x8*)&Ab[(wr * 64 + s * 16 + l16) * BK + quad * 8];
    #pragma unroll
    for (int t = 0; t < 4; ++t)
      bfr[t] = *(const bf16x8*)&Bb[(wc * 64 + t * 16 + l16) * BK + quad * 8];
    #pragma unroll
    for (int s = 0; s < 4; ++s)
      #pragma unroll
      for (int t = 0; t < 4; ++t)
        acc[s][t] = __builtin_amdgcn_mfma_f32_16x16x32_bf16(af[s], bfr[t], acc[s][t], 0, 0, 0);
    __syncthreads();
  }

  #pragma unroll
  for (int s = 0; s < 4; ++s)
    #pragma unroll
    for (int r = 0; r < 4; ++r) {
      int row = m0 + wr * 64 + s * 16 + quad * 4 + r;
      if (row < Mstore) {
        size_t rb = (size_t)row * Ncols + n0 + wc * 64;
        #pragma unroll
        for (int t = 0; t < 4; ++t) {
          float val = acc[s][t][r];
          if constexpr (sizeof(OutT) == 2)
            C[rb + t * 16 + l16] = (OutT)(unsigned short)f2bf(val);
          else
            C[rb + t * 16 + l16] = (OutT)val;
        }
      }
    }
}

// ------------- RoPE v2 (tiled, coalesced): block = (64 tokens) x (one bh) -------------
__global__ __launch_bounds__(256) void rope_kernel(const short* __restrict__ qkv,
                                                   short* __restrict__ qg,
                                                   short* __restrict__ kg,
                                                   short* __restrict__ vT) {
  int bh = blockIdx.y;              // 0..31
  int n0 = blockIdx.x * 64;         // 33 tiles cover NPAD
  int b = bh >> 4, h = bh & 15;
  int t = threadIdx.x;
  int nl = t >> 2;                  // token within tile
  int p  = t & 3;                   // dh part: pairs (p*8+j, p*8+j+32)
  int n  = n0 + nl;
  size_t hb = (size_t)bh * NPAD * DH;
  size_t ob = hb + (size_t)n * DH;

  __shared__ short Vt[64][66];      // [n-local][dh], pad 2 to de-stride column reads

  bf16x8 oq1 = {}, oq2 = {}, ok1 = {}, ok2 = {};
  short v1s[8] = {}, v2s[8] = {};
  if (n < N_) {
    size_t ib = ((size_t)(b * N_ + n)) * 3072 + h * DH;
    bf16x8 q1v = *(const bf16x8*)(qkv + ib + p * 8);
    bf16x8 q2v = *(const bf16x8*)(qkv + ib + 32 + p * 8);
    bf16x8 k1v = *(const bf16x8*)(qkv + ib + 1024 + p * 8);
    bf16x8 k2v = *(const bf16x8*)(qkv + ib + 1024 + 32 + p * 8);
    bf16x8 v1v = *(const bf16x8*)(qkv + ib + 2048 + p * 8);
    bf16x8 v2v = *(const bf16x8*)(qkv + ib + 2048 + 32 + p * 8);
    #pragma unroll
    for (int j = 0; j < 8; ++j) {
      int i = p * 8 + j;
      float q1 = bf2f(q1v[j]), q2 = bf2f(q2v[j]);
      float k1 = bf2f(k1v[j]), k2 = bf2f(k2v[j]);
      if (n > 0) {              // cls token excluded from RoPE
        float ang = (float)(n - 1) * powf(10000.0f, -(float)i * (1.0f / 32.0f));
        float sn, cs; sincosf(ang, &sn, &cs);
        float nq1 = q1 * cs - q2 * sn, nq2 = q2 * cs + q1 * sn;
        float nk1 = k1 * cs - k2 * sn, nk2 = k2 * cs + k1 * sn;
        q1 = nq1; q2 = nq2; k1 = nk1; k2 = nk2;
      }
      oq1[j] = f2bf(q1 * QSCALE); oq2[j] = f2bf(q2 * QSCALE);  // scale*log2e folded into q
      ok1[j] = f2bf(k1); ok2[j] = f2bf(k2);
      v1s[j] = v1v[j]; v2s[j] = v2v[j];
    }
  }
  // q/k row-major stores (zero rows for padding)
  *(bf16x8*)(qg + ob + p * 8)      = oq1;
  *(bf16x8*)(qg + ob + 32 + p * 8) = oq2;
  *(bf16x8*)(kg + ob + p * 8)      = ok1;
  *(bf16x8*)(kg + ob + 32 + p * 8) = ok2;
  // stage V to LDS
  #pragma unroll
  for (int j = 0; j < 8; ++j) {
    Vt[nl][p * 8 + j]      = v1s[j];
    Vt[nl][32 + p * 8 + j] = v2s[j];
  }
  __syncthreads();
  // vT write: thread covers dh=t>>2, 16 consecutive tokens
  int d = t >> 2, c0 = (t & 3) * 16;
  bf16x8 w0, w1;
  #pragma unroll
  for (int m = 0; m < 8; ++m) { w0[m] = Vt[c0 + m][d]; w1[m] = Vt[c0 + 8 + m][d]; }
  *(bf16x8*)(vT + hb + (size_t)d * NPAD + n0 + c0)     = w0;
  *(bf16x8*)(vT + hb + (size_t)d * NPAD + n0 + c0 + 8) = w1;
}

// ------------- flash attention v5: barrier-free, K direct from L2, K-split(2) -------------
#define PSTRIDE 72

__global__ __launch_bounds__(256, 4) void attn_kernel(const short* __restrict__ qg,
                                                      const short* __restrict__ kg,
                                                      const short* __restrict__ vT,
                                                      short* __restrict__ Opart,
                                                      float* __restrict__ lpart) {
  // XCD-clustered decode: blk&7 -> XCD (round-robin heuristic)
  int blk = blockIdx.x;             // 0..1087
  int xcd = blk & 7;
  int t_  = blk >> 3;               // 0..135
  int bh  = xcd * 4 + (t_ & 3);     // 4 heads per XCD
  int u   = t_ >> 2;                // 0..33
  int ks  = (u >= 17) ? 1 : 0;
  int qblk = u - ks * 17;           // 0..16
  int kt0 = ks * 17, kt1 = ks ? 32 : 16;   // inclusive key-tile range

  int lane = threadIdx.x & 63, wid = threadIdx.x >> 6;
  int quad = lane >> 4, l16 = lane & 15;
  int q0 = qblk * 128 + wid * 32;          // this wave's 32 query rows
  size_t hb = (size_t)bh * NPAD * DH;
  const short* kg_hb = kg + hb;
  const short* vT_hb = vT + hb;

  __shared__ __align__(16) short Pbuf[4][32 * PSTRIDE];  // 18.4 KB, wave-private
  short* Pw = &Pbuf[wid][0];

  int qr0 = q0 + l16;      if (qr0 >= NPAD) qr0 = 0;   // clamp; never stored
  int qr1 = q0 + 16 + l16; if (qr1 >= NPAD) qr1 = 0;
  const short* qp0 = qg + hb + (size_t)qr0 * DH;
  const short* qp1 = qg + hb + (size_t)qr1 * DH;
  bf16x8 bq0 = *(const bf16x8*)(qp0 + quad * 8);
  bf16x8 bq1 = *(const bf16x8*)(qp0 + 32 + quad * 8);
  bf16x8 cq0 = *(const bf16x8*)(qp1 + quad * 8);
  bf16x8 cq1 = *(const bf16x8*)(qp1 + 32 + quad * 8);

  f32x4 o[2][4] = {};       // O^T[dh=d*16+quad*4+r][q = q0+qs*16+l16]
  float lrun[2] = {0.0f, 0.0f};

  for (int kt = kt0; kt <= kt1; ++kt) {
    int k0 = kt * 64;
    // ---- K frags direct from global (L2-hit; latency hidden by TLP) ----
    bf16x8 kf[8];
    #pragma unroll
    for (int t = 0; t < 4; ++t) {
      const short* kp = kg_hb + (size_t)(k0 + t * 16 + l16) * DH + quad * 8;
      kf[2 * t]     = *(const bf16x8*)kp;
      kf[2 * t + 1] = *(const bf16x8*)(kp + 32);
    }
    // ---- per 16-key subtile: QK MFMA -> exp2 -> pack -> wave-private LDS ----
    float vsum0 = 0.0f, vsum1 = 0.0f;
    bool tail = (k0 + 64 > N_);
    #pragma unroll
    for (int t = 0; t < 4; ++t) {
      f32x4 z = {};
      f32x4 sa = __builtin_amdgcn_mfma_f32_16x16x32_bf16(kf[2 * t], bq0, z, 0, 0, 0);
      sa = __builtin_amdgcn_mfma_f32_16x16x32_bf16(kf[2 * t + 1], bq1, sa, 0, 0, 0);
      f32x4 sb = __builtin_amdgcn_mfma_f32_16x16x32_bf16(kf[2 * t], cq0, z, 0, 0, 0);
      sb = __builtin_amdgcn_mfma_f32_16x16x32_bf16(kf[2 * t + 1], cq1, sb, 0, 0, 0);
      if (tail) {
        #pragma unroll
        for (int r = 0; r < 4; ++r)
          if (k0 + t * 16 + quad * 4 + r >= N_) { sa[r] = -1e30f; sb[r] = -1e30f; }
      }
      float a0 = hexp2(sa[0]), a1 = hexp2(sa[1]), a2 = hexp2(sa[2]), a3 = hexp2(sa[3]);
      float b0 = hexp2(sb[0]), b1 = hexp2(sb[1]), b2 = hexp2(sb[2]), b3 = hexp2(sb[3]);
      vsum0 += (a0 + a1) + (a2 + a3);
      vsum1 += (b0 + b1) + (b2 + b3);
      int pcol = t * 16 + quad * 4;
      *(unsigned*)&Pw[l16 * PSTRIDE + pcol]            = pack_trunc(a0, a1);
      *(unsigned*)&Pw[l16 * PSTRIDE + pcol + 2]        = pack_trunc(a2, a3);
      *(unsigned*)&Pw[(16 + l16) * PSTRIDE + pcol]     = pack_trunc(b0, b1);
      *(unsigned*)&Pw[(16 + l16) * PSTRIDE + pcol + 2] = pack_trunc(b2, b3);
    }
    vsum0 += __shfl_xor(vsum0, 16, 64); vsum0 += __shfl_xor(vsum0, 32, 64);
    vsum1 += __shfl_xor(vsum1, 16, 64); vsum1 += __shfl_xor(vsum1, 32, 64);
    lrun[0] += vsum0; lrun[1] += vsum1;
    // ---- O^T += V^T * P^T (V direct from L2; P from wave-private LDS) ----
    #pragma unroll
    for (int c = 0; c < 2; ++c) {
      bf16x8 vf[4];
      #pragma unroll
      for (int d = 0; d < 4; ++d)
        vf[d] = *(const bf16x8*)(vT_hb + (size_t)(d * 16 + l16) * NPAD + k0 + c * 32 + quad * 8);
      bf16x8 bp0 = *(const bf16x8*)&Pw[l16 * PSTRIDE + c * 32 + quad * 8];
      bf16x8 bp1 = *(const bf16x8*)&Pw[(16 + l16) * PSTRIDE + c * 32 + quad * 8];
      #pragma unroll
      for (int d = 0; d < 4; ++d) {
        o[0][d] = __builtin_amdgcn_mfma_f32_16x16x32_bf16(vf[d], bp0, o[0][d], 0, 0, 0);
        o[1][d] = __builtin_amdgcn_mfma_f32_16x16x32_bf16(vf[d], bp1, o[1][d], 0, 0, 0);
      }
    }
  }

  // epilogue: unnormalized partial write. Opart[ks][bh][NPAD][64] bf16, lpart[ks][bh][NPAD] fp32
  #pragma unroll
  for (int qs = 0; qs < 2; ++qs) {
    int qrow = q0 + qs * 16 + l16;
    if (qrow < N_) {
      size_t ob = (((size_t)ks * 32 + bh) * NPAD + qrow) * 64;
      #pragma unroll
      for (int d = 0; d < 4; ++d) {
        short4 st;
        st.x = f2bf(o[qs][d][0]);
        st.y = f2bf(o[qs][d][1]);
        st.z = f2bf(o[qs][d][2]);
        st.w = f2bf(o[qs][d][3]);
        *(short4*)(Opart + ob + d * 16 + quad * 4) = st;
      }
      if (quad == 0) lpart[((size_t)ks * 32 + bh) * NPAD + qrow] = lrun[qs];
    }
  }
}

// ------------- combine: attn_out = (O0+O1)/(l0+l1), bf16 -------------
__global__ __launch_bounds__(256) void combine_kernel(const short* __restrict__ Opart,
                                                      const float* __restrict__ lpart,
                                                      short* __restrict__ attn_out) {
  int idx = blockIdx.x * 256 + threadIdx.x;
  const int total = 32 * N_ * 16;          // 4 dh elems per thread
  if (idx >= total) return;
  int c4 = idx & 15;
  int t = idx >> 4;
  int n = t % N_;
  int bh = t / N_;
  int b = bh >> 4, h = bh & 15;
  const size_t halfO = (size_t)32 * NPAD * 64;
  size_t off = ((size_t)bh * NPAD + n) * 64 + c4 * 4;
  short4 a  = *(const short4*)(Opart + off);
  short4 bb = *(const short4*)(Opart + halfO + off);
  float la = lpart[(size_t)bh * NPAD + n];
  float lb = lpart[(size_t)32 * NPAD + (size_t)bh * NPAD + n];
  float inv = 1.0f / (la + lb);
  short4 st;
  st.x = f2bf((bf2f(a.x) + bf2f(bb.x)) * inv);
  st.y = f2bf((bf2f(a.y) + bf2f(bb.y)) * inv);
  st.z = f2bf((bf2f(a.z) + bf2f(bb.z)) * inv);
  st.w = f2bf((bf2f(a.w) + bf2f(bb.w)) * inv);
  size_t rowb = ((size_t)(b * N_ + n)) * (H_ * DH) + h * DH + c4 * 4;
  *(short4*)(attn_out + rowb) = st;
}

// ---------------- launcher ----------------
extern "C" void kernel_launch(void* const* d_in, const int* in_sizes, int n_in,
                              void* d_out, int out_size, void* d_ws, size_t ws_size,
                              hipStream_t stream) {
  const float* x     = (const float*)d_in[0];
  const float* gamma = (const float*)d_in[1];
  const float* beta  = (const float*)d_in[2];
  const float* w_qkv = (const float*)d_in[3];
  const float* w_out = (const float*)d_in[4];

  short* wqkvT = (short*)d_ws;                         // [3072][1024]
  short* woutT = wqkvT + (size_t)3072 * 1024;          // [1024][1024]
  short* xn    = woutT + (size_t)1024 * 1024;          // [4224][1024] (aliased as attn_out later)
  short* qkv   = xn    + (size_t)MPAD * 1024;          // [4224][3072] (aliased as Opart/lpart later)
  short* qg    = qkv   + (size_t)MPAD * 3072;          // [2][16][2112][64]
  short* kg    = qg    + (size_t)B_ * H_ * NPAD * DH;
  short* vTg   = kg    + (size_t)B_ * H_ * NPAD * DH;  // [2][16][64][2112]
  short* attn_out = xn;                                // xn dead after QKV GEMM
  short* Opart = qkv;                                  // [2][32][2112][64] bf16 (qkv dead after rope)
  float* lpart = (float*)(qkv + (size_t)2 * 32 * NPAD * 64);  // [2][32][2112] fp32

  ln_kernel<<<MROWS, 256, 0, stream>>>(x, gamma, beta, xn);
  transpose_cast<<<(1024 * 3072 + 255) / 256, 256, 0, stream>>>(w_qkv, wqkvT, 1024, 3072);
  transpose_cast<<<(1024 * 1024 + 255) / 256, 256, 0, stream>>>(w_out, woutT, 1024, 1024);
  {
    dim3 g(MPAD / 128, 3072 / 128);        // 33 x 24
    gemm128<unsigned short><<<g, 256, 0, stream>>>(xn, wqkvT, (unsigned short*)qkv, MROWS, 3072, 1024);
  }
  {
    dim3 g(33, 32);                        // 64-token tiles x (b,h)
    rope_kernel<<<g, 256, 0, stream>>>(qkv, qg, kg, vTg);
  }
  attn_kernel<<<8 * 4 * 17 * 2, 256, 0, stream>>>(qg, kg, vTg, Opart, lpart);   // 1088 wg
  combine_kernel<<<(32 * N_ * 16 + 255) / 256, 256, 0, stream>>>(Opart, lpart, attn_out);
  {
    dim3 g(MPAD / 128, 1024 / 128);        // 33 x 8
    gemm128<float><<<g, 256, 0, stream>>>(attn_out, woutT, (float*)d_out, MROWS, 1024, 1024);
  }
}

// Round 11
// 326.313 us; speedup vs baseline: 1.0965x; 1.0965x over previous
//
#include <hip/hip_runtime.h>

// ---- problem constants ----
#define B_    2
#define N_    2049
#define NPAD  2112          // keys padded to multiple of 64
#define D_    1024
#define H_    16
#define DH    64
#define MROWS (B_ * N_)     // 4098
#define MPAD  4224          // MROWS padded to multiple of 128 (GEMM block tile)
#define QSCALE 0.18033688011117674f   // 0.125 * log2(e): softmax in exp2 domain

using bf16x8 = __attribute__((ext_vector_type(8))) short;
using f32x4  = __attribute__((ext_vector_type(4))) float;

#define AS1 __attribute__((address_space(1)))
#define AS3 __attribute__((address_space(3)))

__device__ __forceinline__ float bf2f(short s) {
  union { unsigned u; float f; } a; a.u = ((unsigned)(unsigned short)s) << 16; return a.f;
}
__device__ __forceinline__ short f2bf(float f) {
  union { float f; unsigned u; } a; a.f = f;
  unsigned r = a.u + 0x7fffu + ((a.u >> 16) & 1u);   // round-to-nearest-even
  return (short)(r >> 16);
}
// truncation pack of two fp32 -> bf16x2
__device__ __forceinline__ unsigned pack_trunc(float lo, float hi) {
  union { float f; unsigned u; } a, b; a.f = lo; b.f = hi;
  return (b.u & 0xffff0000u) | (a.u >> 16);
}
// hardware 2^x (v_exp_f32)
__device__ __forceinline__ float hexp2(float x) { return __builtin_amdgcn_exp2f(x); }
// async global->LDS DMA, 16 B/lane; LDS dst is wave-uniform base (+lane*16 by HW)
__device__ __forceinline__ void dma16(const short* g, AS3 short* l) {
  __builtin_amdgcn_global_load_lds((const AS1 unsigned*)g, (AS3 unsigned*)l, 16, 0, 0);
}

// ---------------- LayerNorm: fp32 in -> bf16 out ----------------
__global__ __launch_bounds__(256) void ln_kernel(const float* __restrict__ x,
                                                 const float* __restrict__ gamma,
                                                 const float* __restrict__ beta,
                                                 short* __restrict__ xn) {
  int row = blockIdx.x;
  int tid = threadIdx.x;
  const float4 v = ((const float4*)(x + (size_t)row * D_))[tid];
  float s  = v.x + v.y + v.z + v.w;
  float ss = v.x * v.x + v.y * v.y + v.z * v.z + v.w * v.w;
  for (int o = 1; o < 64; o <<= 1) { s += __shfl_xor(s, o, 64); ss += __shfl_xor(ss, o, 64); }
  __shared__ float sb[4], s2b[4];
  int wid = tid >> 6;
  if ((tid & 63) == 0) { sb[wid] = s; s2b[wid] = ss; }
  __syncthreads();
  float st  = sb[0] + sb[1] + sb[2] + sb[3];
  float sst = s2b[0] + s2b[1] + s2b[2] + s2b[3];
  float mu  = st * (1.0f / D_);
  float var = sst * (1.0f / D_) - mu * mu;
  float rs  = rsqrtf(var + 1e-5f);
  const float4 g  = ((const float4*)gamma)[tid];
  const float4 be = ((const float4*)beta)[tid];
  short4 o4;
  o4.x = f2bf((v.x - mu) * rs * g.x + be.x);
  o4.y = f2bf((v.y - mu) * rs * g.y + be.y);
  o4.z = f2bf((v.z - mu) * rs * g.z + be.z);
  o4.w = f2bf((v.w - mu) * rs * g.w + be.w);
  ((short4*)(xn + (size_t)row * D_))[tid] = o4;
}

// ------------- transpose+cast: fp32 [K][Nn] -> bf16 [Nn][K] -------------
__global__ __launch_bounds__(256) void transpose_cast(const float* __restrict__ in,
                                                      short* __restrict__ out,
                                                      int K, int Nn) {
  int idx = blockIdx.x * 256 + threadIdx.x;
  if (idx >= K * Nn) return;
  int kk = idx / Nn, nn = idx - kk * Nn;
  out[(size_t)nn * K + kk] = f2bf(in[idx]);
}

// ------------- m97-style 128x128 GEMM: C[M][Ncols] = A[M][K] * BT[Ncols][K]^T -------------
#define BM 128
#define BK 32
template <typename OutT>
__global__ __launch_bounds__(256) void gemm128(const short* __restrict__ A,
                                               const short* __restrict__ BT,
                                               OutT* __restrict__ C,
                                               int Mstore, int Ncols, int K) {
  int lane = threadIdx.x & 63, wid = threadIdx.x >> 6;
  int quad = lane >> 4, l16 = lane & 15;
  int wr = wid >> 1, wc = wid & 1;
  int m0 = blockIdx.x * BM;
  int n0 = blockIdx.y * BM;

  __shared__ __align__(16) short Abuf[2][BM * BK];   // [row][k] row-major, 8 KB each
  __shared__ __align__(16) short Bbuf[2][BM * BK];
  AS3 short* AbufL = (AS3 short*)&Abuf[0][0];
  AS3 short* BbufL = (AS3 short*)&Bbuf[0][0];

  f32x4 acc[4][4] = {};

  int lrow = lane >> 2, lcol8 = (lane & 3) * 8;
  const short* Ag = A  + (size_t)(m0 + lrow) * K + lcol8;
  const short* Bg = BT + (size_t)(n0 + lrow) * K + lcol8;

  auto stage = [&](int kt, int bb) {
    int k0 = kt * BK;
    #pragma unroll
    for (int i = 0; i < 2; ++i) {
      int j = wid * 2 + i;                  // slab 0..7 (16 rows each)
      dma16(Ag + (size_t)j * 16 * K + k0, AbufL + bb * (BM * BK) + j * 512);
      dma16(Bg + (size_t)j * 16 * K + k0, BbufL + bb * (BM * BK) + j * 512);
    }
  };

  stage(0, 0);
  __syncthreads();

  int KT = K / BK;
  for (int kt = 0; kt < KT; ++kt) {
    int cur = kt & 1;
    if (kt + 1 < KT) stage(kt + 1, cur ^ 1);
    const short* Ab = &Abuf[cur][0];
    const short* Bb = &Bbuf[cur][0];
    bf16x8 af[4], bfr[4];
    #pragma unroll
    for (int s = 0; s < 4; ++s)
      af[s] = *(const bf16x8*)&Ab[(wr * 64 + s * 16 + l16) * BK + quad * 8];
    #pragma unroll
    for (int t = 0; t < 4; ++t)
      bfr[t] = *(const bf16x8*)&Bb[(wc * 64 + t * 16 + l16) * BK + quad * 8];
    #pragma unroll
    for (int s = 0; s < 4; ++s)
      #pragma unroll
      for (int t = 0; t < 4; ++t)
        acc[s][t] = __builtin_amdgcn_mfma_f32_16x16x32_bf16(af[s], bfr[t], acc[s][t], 0, 0, 0);
    __syncthreads();
  }

  #pragma unroll
  for (int s = 0; s < 4; ++s)
    #pragma unroll
    for (int r = 0; r < 4; ++r) {
      int row = m0 + wr * 64 + s * 16 + quad * 4 + r;
      if (row < Mstore) {
        size_t rb = (size_t)row * Ncols + n0 + wc * 64;
        #pragma unroll
        for (int t = 0; t < 4; ++t) {
          float val = acc[s][t][r];
          if constexpr (sizeof(OutT) == 2)
            C[rb + t * 16 + l16] = (OutT)(unsigned short)f2bf(val);
          else
            C[rb + t * 16 + l16] = (OutT)val;
        }
      }
    }
}

// ------------- RoPE v2 (tiled, coalesced): block = (64 tokens) x (one bh) -------------
__global__ __launch_bounds__(256) void rope_kernel(const short* __restrict__ qkv,
                                                   short* __restrict__ qg,
                                                   short* __restrict__ kg,
                                                   short* __restrict__ vT) {
  int bh = blockIdx.y;              // 0..31
  int n0 = blockIdx.x * 64;         // 33 tiles cover NPAD
  int b = bh >> 4, h = bh & 15;
  int t = threadIdx.x;
  int nl = t >> 2;                  // token within tile
  int p  = t & 3;                   // dh part: pairs (p*8+j, p*8+j+32)
  int n  = n0 + nl;
  size_t hb = (size_t)bh * NPAD * DH;
  size_t ob = hb + (size_t)n * DH;

  __shared__ short Vt[64][66];      // [n-local][dh], pad 2 to de-stride column reads

  bf16x8 oq1 = {}, oq2 = {}, ok1 = {}, ok2 = {};
  short v1s[8] = {}, v2s[8] = {};
  if (n < N_) {
    size_t ib = ((size_t)(b * N_ + n)) * 3072 + h * DH;
    bf16x8 q1v = *(const bf16x8*)(qkv + ib + p * 8);
    bf16x8 q2v = *(const bf16x8*)(qkv + ib + 32 + p * 8);
    bf16x8 k1v = *(const bf16x8*)(qkv + ib + 1024 + p * 8);
    bf16x8 k2v = *(const bf16x8*)(qkv + ib + 1024 + 32 + p * 8);
    bf16x8 v1v = *(const bf16x8*)(qkv + ib + 2048 + p * 8);
    bf16x8 v2v = *(const bf16x8*)(qkv + ib + 2048 + 32 + p * 8);
    #pragma unroll
    for (int j = 0; j < 8; ++j) {
      int i = p * 8 + j;
      float q1 = bf2f(q1v[j]), q2 = bf2f(q2v[j]);
      float k1 = bf2f(k1v[j]), k2 = bf2f(k2v[j]);
      if (n > 0) {              // cls token excluded from RoPE
        float ang = (float)(n - 1) * powf(10000.0f, -(float)i * (1.0f / 32.0f));
        float sn, cs; sincosf(ang, &sn, &cs);
        float nq1 = q1 * cs - q2 * sn, nq2 = q2 * cs + q1 * sn;
        float nk1 = k1 * cs - k2 * sn, nk2 = k2 * cs + k1 * sn;
        q1 = nq1; q2 = nq2; k1 = nk1; k2 = nk2;
      }
      oq1[j] = f2bf(q1 * QSCALE); oq2[j] = f2bf(q2 * QSCALE);  // scale*log2e folded into q
      ok1[j] = f2bf(k1); ok2[j] = f2bf(k2);
      v1s[j] = v1v[j]; v2s[j] = v2v[j];
    }
  }
  // q/k row-major stores (zero rows for padding)
  *(bf16x8*)(qg + ob + p * 8)      = oq1;
  *(bf16x8*)(qg + ob + 32 + p * 8) = oq2;
  *(bf16x8*)(kg + ob + p * 8)      = ok1;
  *(bf16x8*)(kg + ob + 32 + p * 8) = ok2;
  // stage V to LDS
  #pragma unroll
  for (int j = 0; j < 8; ++j) {
    Vt[nl][p * 8 + j]      = v1s[j];
    Vt[nl][32 + p * 8 + j] = v2s[j];
  }
  __syncthreads();
  // vT write: thread covers dh=t>>2, 16 consecutive tokens
  int d = t >> 2, c0 = (t & 3) * 16;
  bf16x8 w0, w1;
  #pragma unroll
  for (int m = 0; m < 8; ++m) { w0[m] = Vt[c0 + m][d]; w1[m] = Vt[c0 + 8 + m][d]; }
  *(bf16x8*)(vT + hb + (size_t)d * NPAD + n0 + c0)     = w0;
  *(bf16x8*)(vT + hb + (size_t)d * NPAD + n0 + c0 + 8) = w1;
}

// ------------- flash attention v6: r8 DMA structure + chunked wave-private P -------------
// K-tile via global_load_lds double-buffer (shared by 4 waves, 1 barrier/iter).
// P kept in packed regs, spilled per 32-key chunk to a small wave-private LDS slab
// (2 qs x 16 rows x 40 shorts -> b128-aligned reads), V loaded once per chunk.
#define PST2 40   // chunk row stride in shorts (80 B: 16B-aligned b128 reads)

__global__ __launch_bounds__(256, 4) void attn_kernel(const short* __restrict__ qg,
                                                      const short* __restrict__ kg,
                                                      const short* __restrict__ vT,
                                                      short* __restrict__ Opart,
                                                      float* __restrict__ lpart) {
  // XCD-clustered decode: blk&7 -> XCD (round-robin heuristic)
  int blk = blockIdx.x;             // 0..1087
  int xcd = blk & 7;
  int t_  = blk >> 3;               // 0..135
  int bh  = xcd * 4 + (t_ & 3);     // 4 heads per XCD
  int u   = t_ >> 2;                // 0..33
  int ks  = (u >= 17) ? 1 : 0;
  int qblk = u - ks * 17;           // 0..16
  int kt0 = ks * 17, kt1 = ks ? 32 : 16;   // inclusive key-tile range

  int lane = threadIdx.x & 63, wid = threadIdx.x >> 6;
  int quad = lane >> 4, l16 = lane & 15;
  int q0 = qblk * 128 + wid * 32;          // this wave's 32 query rows
  size_t hb = (size_t)bh * NPAD * DH;
  const short* kg_hb = kg + hb;
  const short* vT_hb = vT + hb;

  __shared__ __align__(16) short Kbuf[2][8 * 512];        // 16 KB
  __shared__ __align__(16) short Pbuf[4][2 * 16 * PST2];  // 10 KB, wave-private chunks
  AS3 short* KbufL = (AS3 short*)&Kbuf[0][0];
  short* Pw = &Pbuf[wid][0];

  int qr0 = q0 + l16;      if (qr0 >= NPAD) qr0 = 0;   // clamp; never stored
  int qr1 = q0 + 16 + l16; if (qr1 >= NPAD) qr1 = 0;
  const short* qp0 = qg + hb + (size_t)qr0 * DH;
  const short* qp1 = qg + hb + (size_t)qr1 * DH;
  bf16x8 bq0 = *(const bf16x8*)(qp0 + quad * 8);
  bf16x8 bq1 = *(const bf16x8*)(qp0 + 32 + quad * 8);
  bf16x8 cq0 = *(const bf16x8*)(qp1 + quad * 8);
  bf16x8 cq1 = *(const bf16x8*)(qp1 + 32 + quad * 8);

  f32x4 o[2][4] = {};       // O^T[dh=d*16+quad*4+r][q = q0+qs*16+l16]
  float lrun[2] = {0.0f, 0.0f};

  auto stage = [&](int kt, int bb) {
    int k0 = kt * 64;
    #pragma unroll
    for (int i = 0; i < 2; ++i) {
      int j = wid * 2 + i;
      int t = j >> 1, half = j & 1;
      const short* g = kg_hb + (size_t)(k0 + t * 16 + l16) * DH + half * 32 + quad * 8;
      dma16(g, KbufL + bb * 4096 + j * 512);
    }
  };

  stage(kt0, 0);
  __syncthreads();

  for (int kt = kt0; kt <= kt1; ++kt) {
    int cur = (kt - kt0) & 1;
    if (kt < kt1) stage(kt + 1, cur ^ 1);
    int k0 = kt * 64;

    // ---- S^T = K * Q^T : K-frags from LDS ----
    const short* Kc = &Kbuf[cur][0];
    f32x4 s[2][4] = {};
    #pragma unroll
    for (int t = 0; t < 4; ++t) {
      bf16x8 kf0 = *(const bf16x8*)&Kc[(t * 2 + 0) * 512 + lane * 8];
      bf16x8 kf1 = *(const bf16x8*)&Kc[(t * 2 + 1) * 512 + lane * 8];
      s[0][t] = __builtin_amdgcn_mfma_f32_16x16x32_bf16(kf0, bq0, s[0][t], 0, 0, 0);
      s[0][t] = __builtin_amdgcn_mfma_f32_16x16x32_bf16(kf1, bq1, s[0][t], 0, 0, 0);
      s[1][t] = __builtin_amdgcn_mfma_f32_16x16x32_bf16(kf0, cq0, s[1][t], 0, 0, 0);
      s[1][t] = __builtin_amdgcn_mfma_f32_16x16x32_bf16(kf1, cq1, s[1][t], 0, 0, 0);
    }
    // mask invalid keys (only final tile; wave-uniform branch)
    if (k0 + 64 > N_) {
      #pragma unroll
      for (int qs = 0; qs < 2; ++qs)
        #pragma unroll
        for (int t = 0; t < 4; ++t)
          #pragma unroll
          for (int r = 0; r < 4; ++r)
            if (k0 + t * 16 + quad * 4 + r >= N_) s[qs][t][r] = -1e30f;
    }
    // ---- p = 2^s (fixed-max softmax, exp2 domain), pack to regs, row-sum ----
    unsigned pk[2][4][2];
    #pragma unroll
    for (int qs = 0; qs < 2; ++qs) {
      float vsum = 0.0f;
      #pragma unroll
      for (int t = 0; t < 4; ++t) {
        float p0 = hexp2(s[qs][t][0]), p1 = hexp2(s[qs][t][1]);
        float p2 = hexp2(s[qs][t][2]), p3 = hexp2(s[qs][t][3]);
        vsum += (p0 + p1) + (p2 + p3);
        pk[qs][t][0] = pack_trunc(p0, p1);
        pk[qs][t][1] = pack_trunc(p2, p3);
      }
      vsum += __shfl_xor(vsum, 16, 64);
      vsum += __shfl_xor(vsum, 32, 64);
      lrun[qs] += vsum;
    }
    // ---- per 32-key chunk: spill P slab (both qs), load V once, PV both qs ----
    #pragma unroll
    for (int c = 0; c < 2; ++c) {
      #pragma unroll
      for (int qs = 0; qs < 2; ++qs) {
        int pr = (qs * 16 + l16) * PST2;
        *(unsigned*)&Pw[pr + quad * 4]          = pk[qs][2 * c][0];
        *(unsigned*)&Pw[pr + quad * 4 + 2]      = pk[qs][2 * c][1];
        *(unsigned*)&Pw[pr + 16 + quad * 4]     = pk[qs][2 * c + 1][0];
        *(unsigned*)&Pw[pr + 16 + quad * 4 + 2] = pk[qs][2 * c + 1][1];
      }
      bf16x8 vf[4];
      #pragma unroll
      for (int d = 0; d < 4; ++d)
        vf[d] = *(const bf16x8*)(vT_hb + (size_t)(d * 16 + l16) * NPAD + k0 + c * 32 + quad * 8);
      bf16x8 bp0 = *(const bf16x8*)&Pw[l16 * PST2 + quad * 8];
      bf16x8 bp1 = *(const bf16x8*)&Pw[(16 + l16) * PST2 + quad * 8];
      #pragma unroll
      for (int d = 0; d < 4; ++d) {
        o[0][d] = __builtin_amdgcn_mfma_f32_16x16x32_bf16(vf[d], bp0, o[0][d], 0, 0, 0);
        o[1][d] = __builtin_amdgcn_mfma_f32_16x16x32_bf16(vf[d], bp1, o[1][d], 0, 0, 0);
      }
    }
    __syncthreads();   // DMA kt+1 complete; all waves done with Kbuf[cur]
  }

  // epilogue: unnormalized partial write. Opart[ks][bh][NPAD][64] bf16, lpart[ks][bh][NPAD] fp32
  #pragma unroll
  for (int qs = 0; qs < 2; ++qs) {
    int qrow = q0 + qs * 16 + l16;
    if (qrow < N_) {
      size_t ob = (((size_t)ks * 32 + bh) * NPAD + qrow) * 64;
      #pragma unroll
      for (int d = 0; d < 4; ++d) {
        short4 st;
        st.x = f2bf(o[qs][d][0]);
        st.y = f2bf(o[qs][d][1]);
        st.z = f2bf(o[qs][d][2]);
        st.w = f2bf(o[qs][d][3]);
        *(short4*)(Opart + ob + d * 16 + quad * 4) = st;
      }
      if (quad == 0) lpart[((size_t)ks * 32 + bh) * NPAD + qrow] = lrun[qs];
    }
  }
}

// ------------- combine: attn_out = (O0+O1)/(l0+l1), bf16 -------------
__global__ __launch_bounds__(256) void combine_kernel(const short* __restrict__ Opart,
                                                      const float* __restrict__ lpart,
                                                      short* __restrict__ attn_out) {
  int idx = blockIdx.x * 256 + threadIdx.x;
  const int total = 32 * N_ * 16;          // 4 dh elems per thread
  if (idx >= total) return;
  int c4 = idx & 15;
  int t = idx >> 4;
  int n = t % N_;
  int bh = t / N_;
  int b = bh >> 4, h = bh & 15;
  const size_t halfO = (size_t)32 * NPAD * 64;
  size_t off = ((size_t)bh * NPAD + n) * 64 + c4 * 4;
  short4 a  = *(const short4*)(Opart + off);
  short4 bb = *(const short4*)(Opart + halfO + off);
  float la = lpart[(size_t)bh * NPAD + n];
  float lb = lpart[(size_t)32 * NPAD + (size_t)bh * NPAD + n];
  float inv = 1.0f / (la + lb);
  short4 st;
  st.x = f2bf((bf2f(a.x) + bf2f(bb.x)) * inv);
  st.y = f2bf((bf2f(a.y) + bf2f(bb.y)) * inv);
  st.z = f2bf((bf2f(a.z) + bf2f(bb.z)) * inv);
  st.w = f2bf((bf2f(a.w) + bf2f(bb.w)) * inv);
  size_t rowb = ((size_t)(b * N_ + n)) * (H_ * DH) + h * DH + c4 * 4;
  *(short4*)(attn_out + rowb) = st;
}

// ---------------- launcher ----------------
extern "C" void kernel_launch(void* const* d_in, const int* in_sizes, int n_in,
                              void* d_out, int out_size, void* d_ws, size_t ws_size,
                              hipStream_t stream) {
  const float* x     = (const float*)d_in[0];
  const float* gamma = (const float*)d_in[1];
  const float* beta  = (const float*)d_in[2];
  const float* w_qkv = (const float*)d_in[3];
  const float* w_out = (const float*)d_in[4];

  short* wqkvT = (short*)d_ws;                         // [3072][1024]
  short* woutT = wqkvT + (size_t)3072 * 1024;          // [1024][1024]
  short* xn    = woutT + (size_t)1024 * 1024;          // [4224][1024] (aliased as attn_out later)
  short* qkv   = xn    + (size_t)MPAD * 1024;          // [4224][3072] (aliased as Opart/lpart later)
  short* qg    = qkv   + (size_t)MPAD * 3072;          // [2][16][2112][64]
  short* kg    = qg    + (size_t)B_ * H_ * NPAD * DH;
  short* vTg   = kg    + (size_t)B_ * H_ * NPAD * DH;  // [2][16][64][2112]
  short* attn_out = xn;                                // xn dead after QKV GEMM
  short* Opart = qkv;                                  // [2][32][2112][64] bf16 (qkv dead after rope)
  float* lpart = (float*)(qkv + (size_t)2 * 32 * NPAD * 64);  // [2][32][2112] fp32

  ln_kernel<<<MROWS, 256, 0, stream>>>(x, gamma, beta, xn);
  transpose_cast<<<(1024 * 3072 + 255) / 256, 256, 0, stream>>>(w_qkv, wqkvT, 1024, 3072);
  transpose_cast<<<(1024 * 1024 + 255) / 256, 256, 0, stream>>>(w_out, woutT, 1024, 1024);
  {
    dim3 g(MPAD / 128, 3072 / 128);        // 33 x 24
    gemm128<unsigned short><<<g, 256, 0, stream>>>(xn, wqkvT, (unsigned short*)qkv, MROWS, 3072, 1024);
  }
  {
    dim3 g(33, 32);                        // 64-token tiles x (b,h)
    rope_kernel<<<g, 256, 0, stream>>>(qkv, qg, kg, vTg);
  }
  attn_kernel<<<8 * 4 * 17 * 2, 256, 0, stream>>>(qg, kg, vTg, Opart, lpart);   // 1088 wg
  combine_kernel<<<(32 * N_ * 16 + 255) / 256, 256, 0, stream>>>(Opart, lpart, attn_out);
  {
    dim3 g(MPAD / 128, 1024 / 128);        // 33 x 8
    gemm128<float><<<g, 256, 0, stream>>>(attn_out, woutT, (float*)d_out, MROWS, 1024, 1024);
  }
}

// Round 12
// 291.513 us; speedup vs baseline: 1.2274x; 1.1194x over previous
//
#include <hip/hip_runtime.h>

// ---- problem constants ----
#define B_    2
#define N_    2049
#define NPAD  2112          // keys padded to multiple of 64
#define D_    1024
#define H_    16
#define DH    64
#define MROWS (B_ * N_)     // 4098
#define MPAD  4224          // MROWS padded to multiple of 128 (GEMM block tile)
#define QSCALE 0.18033688011117674f   // 0.125 * log2(e): softmax in exp2 domain

using bf16x8 = __attribute__((ext_vector_type(8))) short;
using f32x4  = __attribute__((ext_vector_type(4))) float;

#define AS1 __attribute__((address_space(1)))
#define AS3 __attribute__((address_space(3)))

__device__ __forceinline__ float bf2f(short s) {
  union { unsigned u; float f; } a; a.u = ((unsigned)(unsigned short)s) << 16; return a.f;
}
__device__ __forceinline__ short f2bf(float f) {
  union { float f; unsigned u; } a; a.f = f;
  unsigned r = a.u + 0x7fffu + ((a.u >> 16) & 1u);   // round-to-nearest-even
  return (short)(r >> 16);
}
// truncation pack of two fp32 -> bf16x2
__device__ __forceinline__ unsigned pack_trunc(float lo, float hi) {
  union { float f; unsigned u; } a, b; a.f = lo; b.f = hi;
  return (b.u & 0xffff0000u) | (a.u >> 16);
}
// hardware 2^x (v_exp_f32)
__device__ __forceinline__ float hexp2(float x) { return __builtin_amdgcn_exp2f(x); }
// async global->LDS DMA, 16 B/lane; LDS dst is wave-uniform base (+lane*16 by HW)
__device__ __forceinline__ void dma16(const short* g, AS3 short* l) {
  __builtin_amdgcn_global_load_lds((const AS1 unsigned*)g, (AS3 unsigned*)l, 16, 0, 0);
}

// ---------------- LayerNorm: fp32 in -> bf16 out ----------------
__global__ __launch_bounds__(256) void ln_kernel(const float* __restrict__ x,
                                                 const float* __restrict__ gamma,
                                                 const float* __restrict__ beta,
                                                 short* __restrict__ xn) {
  int row = blockIdx.x;
  int tid = threadIdx.x;
  const float4 v = ((const float4*)(x + (size_t)row * D_))[tid];
  float s  = v.x + v.y + v.z + v.w;
  float ss = v.x * v.x + v.y * v.y + v.z * v.z + v.w * v.w;
  for (int o = 1; o < 64; o <<= 1) { s += __shfl_xor(s, o, 64); ss += __shfl_xor(ss, o, 64); }
  __shared__ float sb[4], s2b[4];
  int wid = tid >> 6;
  if ((tid & 63) == 0) { sb[wid] = s; s2b[wid] = ss; }
  __syncthreads();
  float st  = sb[0] + sb[1] + sb[2] + sb[3];
  float sst = s2b[0] + s2b[1] + s2b[2] + s2b[3];
  float mu  = st * (1.0f / D_);
  float var = sst * (1.0f / D_) - mu * mu;
  float rs  = rsqrtf(var + 1e-5f);
  const float4 g  = ((const float4*)gamma)[tid];
  const float4 be = ((const float4*)beta)[tid];
  short4 o4;
  o4.x = f2bf((v.x - mu) * rs * g.x + be.x);
  o4.y = f2bf((v.y - mu) * rs * g.y + be.y);
  o4.z = f2bf((v.z - mu) * rs * g.z + be.z);
  o4.w = f2bf((v.w - mu) * rs * g.w + be.w);
  ((short4*)(xn + (size_t)row * D_))[tid] = o4;
}

// ------------- LDS-tiled transpose+cast: fp32 [K][Nn] -> bf16 [Nn][K] -------------
// 64x64 tile; coalesced read AND coalesced write (fixes the 2B-stride scatter).
__global__ __launch_bounds__(256) void transpose_tiled(const float* __restrict__ in,
                                                       short* __restrict__ out,
                                                       int K, int Nn) {
  __shared__ float T[64][65];       // +1 pad: column reads hit distinct banks
  int k0 = blockIdx.x * 64;         // K-tile base
  int n0 = blockIdx.y * 64;         // N-tile base
  int t = threadIdx.x;
  int r = t >> 2, c0 = (t & 3) * 16;
  const float* ip = in + (size_t)(k0 + r) * Nn + n0 + c0;
  #pragma unroll
  for (int j = 0; j < 4; ++j) {
    float4 v = *(const float4*)(ip + j * 4);
    T[r][c0 + j * 4 + 0] = v.x; T[r][c0 + j * 4 + 1] = v.y;
    T[r][c0 + j * 4 + 2] = v.z; T[r][c0 + j * 4 + 3] = v.w;
  }
  __syncthreads();
  // write: row n = n0 + (t>>2), orig-k cols c0..c0+15, bf16 coalesced
  bf16x8 w0, w1;
  #pragma unroll
  for (int j = 0; j < 8; ++j) {
    w0[j] = f2bf(T[c0 + j][r]);
    w1[j] = f2bf(T[c0 + 8 + j][r]);
  }
  short* op = out + (size_t)(n0 + r) * K + k0 + c0;
  *(bf16x8*)op = w0;
  *(bf16x8*)(op + 8) = w1;
}

// ------------- m97-style 128x128 GEMM: C[M][Ncols] = A[M][K] * BT[Ncols][K]^T -------------
#define BM 128
#define BK 32
template <typename OutT>
__global__ __launch_bounds__(256) void gemm128(const short* __restrict__ A,
                                               const short* __restrict__ BT,
                                               OutT* __restrict__ C,
                                               int Mstore, int Ncols, int K) {
  int lane = threadIdx.x & 63, wid = threadIdx.x >> 6;
  int quad = lane >> 4, l16 = lane & 15;
  int wr = wid >> 1, wc = wid & 1;
  int m0 = blockIdx.x * BM;
  int n0 = blockIdx.y * BM;

  __shared__ __align__(16) short Abuf[2][BM * BK];   // [row][k] row-major, 8 KB each
  __shared__ __align__(16) short Bbuf[2][BM * BK];
  AS3 short* AbufL = (AS3 short*)&Abuf[0][0];
  AS3 short* BbufL = (AS3 short*)&Bbuf[0][0];

  f32x4 acc[4][4] = {};

  int lrow = lane >> 2, lcol8 = (lane & 3) * 8;
  const short* Ag = A  + (size_t)(m0 + lrow) * K + lcol8;
  const short* Bg = BT + (size_t)(n0 + lrow) * K + lcol8;

  auto stage = [&](int kt, int bb) {
    int k0 = kt * BK;
    #pragma unroll
    for (int i = 0; i < 2; ++i) {
      int j = wid * 2 + i;                  // slab 0..7 (16 rows each)
      dma16(Ag + (size_t)j * 16 * K + k0, AbufL + bb * (BM * BK) + j * 512);
      dma16(Bg + (size_t)j * 16 * K + k0, BbufL + bb * (BM * BK) + j * 512);
    }
  };

  stage(0, 0);
  __syncthreads();

  int KT = K / BK;
  for (int kt = 0; kt < KT; ++kt) {
    int cur = kt & 1;
    if (kt + 1 < KT) stage(kt + 1, cur ^ 1);
    const short* Ab = &Abuf[cur][0];
    const short* Bb = &Bbuf[cur][0];
    bf16x8 af[4], bfr[4];
    #pragma unroll
    for (int s = 0; s < 4; ++s)
      af[s] = *(const bf16x8*)&Ab[(wr * 64 + s * 16 + l16) * BK + quad * 8];
    #pragma unroll
    for (int t = 0; t < 4; ++t)
      bfr[t] = *(const bf16x8*)&Bb[(wc * 64 + t * 16 + l16) * BK + quad * 8];
    #pragma unroll
    for (int s = 0; s < 4; ++s)
      #pragma unroll
      for (int t = 0; t < 4; ++t)
        acc[s][t] = __builtin_amdgcn_mfma_f32_16x16x32_bf16(af[s], bfr[t], acc[s][t], 0, 0, 0);
    __syncthreads();
  }

  #pragma unroll
  for (int s = 0; s < 4; ++s)
    #pragma unroll
    for (int r = 0; r < 4; ++r) {
      int row = m0 + wr * 64 + s * 16 + quad * 4 + r;
      if (row < Mstore) {
        size_t rb = (size_t)row * Ncols + n0 + wc * 64;
        #pragma unroll
        for (int t = 0; t < 4; ++t) {
          float val = acc[s][t][r];
          if constexpr (sizeof(OutT) == 2)
            C[rb + t * 16 + l16] = (OutT)(unsigned short)f2bf(val);
          else
            C[rb + t * 16 + l16] = (OutT)val;
        }
      }
    }
}

// ------------- RoPE v2 (tiled, coalesced): block = (64 tokens) x (one bh) -------------
__global__ __launch_bounds__(256) void rope_kernel(const short* __restrict__ qkv,
                                                   short* __restrict__ qg,
                                                   short* __restrict__ kg,
                                                   short* __restrict__ vT) {
  int bh = blockIdx.y;              // 0..31
  int n0 = blockIdx.x * 64;         // 33 tiles cover NPAD
  int b = bh >> 4, h = bh & 15;
  int t = threadIdx.x;
  int nl = t >> 2;                  // token within tile
  int p  = t & 3;                   // dh part: pairs (p*8+j, p*8+j+32)
  int n  = n0 + nl;
  size_t hb = (size_t)bh * NPAD * DH;
  size_t ob = hb + (size_t)n * DH;

  __shared__ short Vt[64][66];      // [n-local][dh], pad 2 to de-stride column reads

  bf16x8 oq1 = {}, oq2 = {}, ok1 = {}, ok2 = {};
  short v1s[8] = {}, v2s[8] = {};
  if (n < N_) {
    size_t ib = ((size_t)(b * N_ + n)) * 3072 + h * DH;
    bf16x8 q1v = *(const bf16x8*)(qkv + ib + p * 8);
    bf16x8 q2v = *(const bf16x8*)(qkv + ib + 32 + p * 8);
    bf16x8 k1v = *(const bf16x8*)(qkv + ib + 1024 + p * 8);
    bf16x8 k2v = *(const bf16x8*)(qkv + ib + 1024 + 32 + p * 8);
    bf16x8 v1v = *(const bf16x8*)(qkv + ib + 2048 + p * 8);
    bf16x8 v2v = *(const bf16x8*)(qkv + ib + 2048 + 32 + p * 8);
    #pragma unroll
    for (int j = 0; j < 8; ++j) {
      int i = p * 8 + j;
      float q1 = bf2f(q1v[j]), q2 = bf2f(q2v[j]);
      float k1 = bf2f(k1v[j]), k2 = bf2f(k2v[j]);
      if (n > 0) {              // cls token excluded from RoPE
        float ang = (float)(n - 1) * powf(10000.0f, -(float)i * (1.0f / 32.0f));
        float sn, cs; sincosf(ang, &sn, &cs);
        float nq1 = q1 * cs - q2 * sn, nq2 = q2 * cs + q1 * sn;
        float nk1 = k1 * cs - k2 * sn, nk2 = k2 * cs + k1 * sn;
        q1 = nq1; q2 = nq2; k1 = nk1; k2 = nk2;
      }
      oq1[j] = f2bf(q1 * QSCALE); oq2[j] = f2bf(q2 * QSCALE);  // scale*log2e folded into q
      ok1[j] = f2bf(k1); ok2[j] = f2bf(k2);
      v1s[j] = v1v[j]; v2s[j] = v2v[j];
    }
  }
  // q/k row-major stores (zero rows for padding)
  *(bf16x8*)(qg + ob + p * 8)      = oq1;
  *(bf16x8*)(qg + ob + 32 + p * 8) = oq2;
  *(bf16x8*)(kg + ob + p * 8)      = ok1;
  *(bf16x8*)(kg + ob + 32 + p * 8) = ok2;
  // stage V to LDS
  #pragma unroll
  for (int j = 0; j < 8; ++j) {
    Vt[nl][p * 8 + j]      = v1s[j];
    Vt[nl][32 + p * 8 + j] = v2s[j];
  }
  __syncthreads();
  // vT write: thread covers dh=t>>2, 16 consecutive tokens
  int d = t >> 2, c0 = (t & 3) * 16;
  bf16x8 w0, w1;
  #pragma unroll
  for (int m = 0; m < 8; ++m) { w0[m] = Vt[c0 + m][d]; w1[m] = Vt[c0 + 8 + m][d]; }
  *(bf16x8*)(vT + hb + (size_t)d * NPAD + n0 + c0)     = w0;
  *(bf16x8*)(vT + hb + (size_t)d * NPAD + n0 + c0 + 8) = w1;
}

// ------------- flash attention (r8 structure, exp2 softmax): K DMA + K-split(2) -------------
struct VTile { bf16x8 f[8]; };
__device__ __forceinline__ void load_vtile(const short* vbase, int k0, int l16, int quad, VTile& t) {
  #pragma unroll
  for (int c = 0; c < 2; ++c)
    #pragma unroll
    for (int d = 0; d < 4; ++d) {
      const short* p = vbase + (size_t)(d * 16 + l16) * NPAD + k0 + c * 32 + quad * 8;
      t.f[c * 4 + d] = *(const bf16x8*)p;
    }
}

#define PSTRIDE 72   // pads P rows so LDS accesses stay ~2-way (free)

__global__ __launch_bounds__(256, 2) void attn_kernel(const short* __restrict__ qg,
                                                      const short* __restrict__ kg,
                                                      const short* __restrict__ vT,
                                                      short* __restrict__ Opart,
                                                      float* __restrict__ lpart) {
  // XCD-clustered decode: blk&7 -> XCD (round-robin heuristic)
  int blk = blockIdx.x;             // 0..1087
  int xcd = blk & 7;
  int t_  = blk >> 3;               // 0..135
  int bh  = xcd * 4 + (t_ & 3);     // 4 heads per XCD
  int u   = t_ >> 2;                // 0..33
  int ks  = (u >= 17) ? 1 : 0;
  int qblk = u - ks * 17;           // 0..16
  int kt0 = ks * 17, kt1 = ks ? 32 : 16;   // inclusive key-tile range

  int lane = threadIdx.x & 63, wid = threadIdx.x >> 6;
  int quad = lane >> 4, l16 = lane & 15;
  int q0 = qblk * 128 + wid * 32;          // this wave's 32 query rows
  size_t hb = (size_t)bh * NPAD * DH;
  const short* kg_hb = kg + hb;
  const short* vT_hb = vT + hb;

  __shared__ __align__(16) short Kbuf[2][8 * 512];       // 16 KB
  __shared__ __align__(16) short Pbuf[4][32 * PSTRIDE];  // 18.4 KB, wave-private
  AS3 short* KbufL = (AS3 short*)&Kbuf[0][0];
  short* Pw = &Pbuf[wid][0];

  int qr0 = q0 + l16;      if (qr0 >= NPAD) qr0 = 0;   // clamp; never stored
  int qr1 = q0 + 16 + l16; if (qr1 >= NPAD) qr1 = 0;
  const short* qp0 = qg + hb + (size_t)qr0 * DH;
  const short* qp1 = qg + hb + (size_t)qr1 * DH;
  bf16x8 bq0 = *(const bf16x8*)(qp0 + quad * 8);
  bf16x8 bq1 = *(const bf16x8*)(qp0 + 32 + quad * 8);
  bf16x8 cq0 = *(const bf16x8*)(qp1 + quad * 8);
  bf16x8 cq1 = *(const bf16x8*)(qp1 + 32 + quad * 8);

  f32x4 o[2][4] = {};       // O^T[dh=d*16+quad*4+r][q = q0+qs*16+l16]
  float lrun[2] = {0.0f, 0.0f};

  auto stage = [&](int kt, int bb) {
    int k0 = kt * 64;
    #pragma unroll
    for (int i = 0; i < 2; ++i) {
      int j = wid * 2 + i;
      int t = j >> 1, half = j & 1;
      const short* g = kg_hb + (size_t)(k0 + t * 16 + l16) * DH + half * 32 + quad * 8;
      dma16(g, KbufL + bb * 4096 + j * 512);
    }
  };

  stage(kt0, 0);
  __syncthreads();

  for (int kt = kt0; kt <= kt1; ++kt) {
    int cur = (kt - kt0) & 1;
    if (kt < kt1) stage(kt + 1, cur ^ 1);
    int k0 = kt * 64;
    VTile v;                                // V loads at iter top (hidden by QK+softmax)
    load_vtile(vT_hb, k0, l16, quad, v);

    // ---- S^T = K * Q^T : K-frags from LDS ----
    const short* Kc = &Kbuf[cur][0];
    f32x4 s[2][4] = {};
    #pragma unroll
    for (int t = 0; t < 4; ++t) {
      bf16x8 kf0 = *(const bf16x8*)&Kc[(t * 2 + 0) * 512 + lane * 8];
      bf16x8 kf1 = *(const bf16x8*)&Kc[(t * 2 + 1) * 512 + lane * 8];
      s[0][t] = __builtin_amdgcn_mfma_f32_16x16x32_bf16(kf0, bq0, s[0][t], 0, 0, 0);
      s[0][t] = __builtin_amdgcn_mfma_f32_16x16x32_bf16(kf1, bq1, s[0][t], 0, 0, 0);
      s[1][t] = __builtin_amdgcn_mfma_f32_16x16x32_bf16(kf0, cq0, s[1][t], 0, 0, 0);
      s[1][t] = __builtin_amdgcn_mfma_f32_16x16x32_bf16(kf1, cq1, s[1][t], 0, 0, 0);
    }
    // mask invalid keys (only final tile; wave-uniform branch)
    if (k0 + 64 > N_) {
      #pragma unroll
      for (int qs = 0; qs < 2; ++qs)
        #pragma unroll
        for (int t = 0; t < 4; ++t)
          #pragma unroll
          for (int r = 0; r < 4; ++r)
            if (k0 + t * 16 + quad * 4 + r >= N_) s[qs][t][r] = -1e30f;
    }
    // ---- p = 2^s (fixed-max softmax, exp2 domain), pack to wave-private LDS, row-sum ----
    #pragma unroll
    for (int qs = 0; qs < 2; ++qs) {
      float vsum = 0.0f;
      int prow = (qs * 16 + l16) * PSTRIDE;
      #pragma unroll
      for (int t = 0; t < 4; ++t) {
        float p0 = hexp2(s[qs][t][0]), p1 = hexp2(s[qs][t][1]);
        float p2 = hexp2(s[qs][t][2]), p3 = hexp2(s[qs][t][3]);
        vsum += (p0 + p1) + (p2 + p3);
        *(unsigned*)&Pw[prow + t * 16 + quad * 4]     = pack_trunc(p0, p1);
        *(unsigned*)&Pw[prow + t * 16 + quad * 4 + 2] = pack_trunc(p2, p3);
      }
      vsum += __shfl_xor(vsum, 16, 64);
      vsum += __shfl_xor(vsum, 32, 64);
      lrun[qs] += vsum;
    }
    // ---- O^T += V^T * P^T (B-frags from wave-private LDS, no barrier) ----
    #pragma unroll
    for (int c = 0; c < 2; ++c) {
      bf16x8 bp0 = *(const bf16x8*)&Pw[(l16)*PSTRIDE + c * 32 + quad * 8];
      bf16x8 bp1 = *(const bf16x8*)&Pw[(16 + l16) * PSTRIDE + c * 32 + quad * 8];
      #pragma unroll
      for (int d = 0; d < 4; ++d) {
        o[0][d] = __builtin_amdgcn_mfma_f32_16x16x32_bf16(v.f[c * 4 + d], bp0, o[0][d], 0, 0, 0);
        o[1][d] = __builtin_amdgcn_mfma_f32_16x16x32_bf16(v.f[c * 4 + d], bp1, o[1][d], 0, 0, 0);
      }
    }
    __syncthreads();   // DMA kt+1 complete; all waves done with Kbuf[cur]
  }

  // epilogue: unnormalized partial write. Opart[ks][bh][NPAD][64] bf16, lpart[ks][bh][NPAD] fp32
  #pragma unroll
  for (int qs = 0; qs < 2; ++qs) {
    int qrow = q0 + qs * 16 + l16;
    if (qrow < N_) {
      size_t ob = (((size_t)ks * 32 + bh) * NPAD + qrow) * 64;
      #pragma unroll
      for (int d = 0; d < 4; ++d) {
        short4 st;
        st.x = f2bf(o[qs][d][0]);
        st.y = f2bf(o[qs][d][1]);
        st.z = f2bf(o[qs][d][2]);
        st.w = f2bf(o[qs][d][3]);
        *(short4*)(Opart + ob + d * 16 + quad * 4) = st;
      }
      if (quad == 0) lpart[((size_t)ks * 32 + bh) * NPAD + qrow] = lrun[qs];
    }
  }
}

// ------------- combine: attn_out = (O0+O1)/(l0+l1), bf16 -------------
__global__ __launch_bounds__(256) void combine_kernel(const short* __restrict__ Opart,
                                                      const float* __restrict__ lpart,
                                                      short* __restrict__ attn_out) {
  int idx = blockIdx.x * 256 + threadIdx.x;
  const int total = 32 * N_ * 16;          // 4 dh elems per thread
  if (idx >= total) return;
  int c4 = idx & 15;
  int t = idx >> 4;
  int n = t % N_;
  int bh = t / N_;
  int b = bh >> 4, h = bh & 15;
  const size_t halfO = (size_t)32 * NPAD * 64;
  size_t off = ((size_t)bh * NPAD + n) * 64 + c4 * 4;
  short4 a  = *(const short4*)(Opart + off);
  short4 bb = *(const short4*)(Opart + halfO + off);
  float la = lpart[(size_t)bh * NPAD + n];
  float lb = lpart[(size_t)32 * NPAD + (size_t)bh * NPAD + n];
  float inv = 1.0f / (la + lb);
  short4 st;
  st.x = f2bf((bf2f(a.x) + bf2f(bb.x)) * inv);
  st.y = f2bf((bf2f(a.y) + bf2f(bb.y)) * inv);
  st.z = f2bf((bf2f(a.z) + bf2f(bb.z)) * inv);
  st.w = f2bf((bf2f(a.w) + bf2f(bb.w)) * inv);
  size_t rowb = ((size_t)(b * N_ + n)) * (H_ * DH) + h * DH + c4 * 4;
  *(short4*)(attn_out + rowb) = st;
}

// ---------------- launcher ----------------
extern "C" void kernel_launch(void* const* d_in, const int* in_sizes, int n_in,
                              void* d_out, int out_size, void* d_ws, size_t ws_size,
                              hipStream_t stream) {
  const float* x     = (const float*)d_in[0];
  const float* gamma = (const float*)d_in[1];
  const float* beta  = (const float*)d_in[2];
  const float* w_qkv = (const float*)d_in[3];
  const float* w_out = (const float*)d_in[4];

  short* wqkvT = (short*)d_ws;                         // [3072][1024]
  short* woutT = wqkvT + (size_t)3072 * 1024;          // [1024][1024]
  short* xn    = woutT + (size_t)1024 * 1024;          // [4224][1024] (aliased as attn_out later)
  short* qkv   = xn    + (size_t)MPAD * 1024;          // [4224][3072] (aliased as Opart/lpart later)
  short* qg    = qkv   + (size_t)MPAD * 3072;          // [2][16][2112][64]
  short* kg    = qg    + (size_t)B_ * H_ * NPAD * DH;
  short* vTg   = kg    + (size_t)B_ * H_ * NPAD * DH;  // [2][16][64][2112]
  short* attn_out = xn;                                // xn dead after QKV GEMM
  short* Opart = qkv;                                  // [2][32][2112][64] bf16 (qkv dead after rope)
  float* lpart = (float*)(qkv + (size_t)2 * 32 * NPAD * 64);  // [2][32][2112] fp32

  ln_kernel<<<MROWS, 256, 0, stream>>>(x, gamma, beta, xn);
  {
    dim3 g(1024 / 64, 3072 / 64);          // LDS-tiled coalesced transpose
    transpose_tiled<<<g, 256, 0, stream>>>(w_qkv, wqkvT, 1024, 3072);
  }
  {
    dim3 g(1024 / 64, 1024 / 64);
    transpose_tiled<<<g, 256, 0, stream>>>(w_out, woutT, 1024, 1024);
  }
  {
    dim3 g(MPAD / 128, 3072 / 128);        // 33 x 24
    gemm128<unsigned short><<<g, 256, 0, stream>>>(xn, wqkvT, (unsigned short*)qkv, MROWS, 3072, 1024);
  }
  {
    dim3 g(33, 32);                        // 64-token tiles x (b,h)
    rope_kernel<<<g, 256, 0, stream>>>(qkv, qg, kg, vTg);
  }
  attn_kernel<<<8 * 4 * 17 * 2, 256, 0, stream>>>(qg, kg, vTg, Opart, lpart);   // 1088 wg
  combine_kernel<<<(32 * N_ * 16 + 255) / 256, 256, 0, stream>>>(Opart, lpart, attn_out);
  {
    dim3 g(MPAD / 128, 1024 / 128);        // 33 x 8
    gemm128<float><<<g, 256, 0, stream>>>(attn_out, woutT, (float*)d_out, MROWS, 1024, 1024);
  }
}